// Round 1
// baseline (68.803 us; speedup 1.0000x reference)
//
#include <hip/hip_runtime.h>
#include <math.h>

// GlobalConvolutionalLayer, fully fused single kernel.
// out[b,i,m] = 0.5*xt_i * sum_l den[b,l]*gw[l]*exp(-xt_i*(g_l-g_m)^2), i < CH(=15)
// out[b,CH,m] = den[b,m].            xt_i = 1 + exp(-xi_i) in (1.37, 3.72).
//
// Mercer/Taylor separation (grid in [0,1], 2*xt*gl*gm <= 7.44):
//   exp(-xt (x-y)^2) = e^{-xt x^2} e^{-xt y^2} sum_n (2 xt)^n (x y)^n / n!
// RTERMS=24 -> absolute tail error ~1e-2 (vs threshold 28.96); all terms >= 0.
//
// One block per (i,b). 1024 threads (16 waves/CU = 4 waves/SIMD; the previous
// 256-thread version ran at 1 wave/SIMD — latency-bound, nothing to hide
// stalls with). With G=4096 each thread owns exactly one float4:
//   phase 1: 3 coalesced float4 loads -> moments S[n] = sum_l W e^{-xt gl^2} gl^n
//   reduce:  wave butterfly + LDS across 16 waves; T[n] = 0.5*xt*(2xt)^n/n! * S[n]
//   phase 2: Horner_24(gm; T) * cached e^{-xt gm^2}; float4 store.
// g and e^{-xt g^2} are register-cached across phases (same indices, l == m).
// No workspace, one launch. grid (CH+1, B) = 256 blocks.

#define RTERMS 24
#define NT 1024
#define NWAVES (NT / 64)
#define LOG2E 1.4426950408889634f

__global__ __launch_bounds__(NT, 4) void gcl_fused(
        const float* __restrict__ density, const float* __restrict__ xi,
        const float* __restrict__ grid, const float* __restrict__ gw,
        float* __restrict__ out, int G, int CH) {
    const int i = blockIdx.x;
    const int b = blockIdx.y;
    const int C = CH + 1;
    const int t = threadIdx.x;
    const int nvec = G >> 2;   // float4 count; == NT when G == 4096

    if (i == CH) {  // raw density channel: vectorized row copy
        const float4* src = (const float4*)(density + (size_t)b * G);
        float4* dst = (float4*)(out + ((size_t)b * C + CH) * G);
        for (int v = t; v < nvec; v += NT) dst[v] = src[v];
        return;
    }

    const float xt = 1.0f + __expf(-xi[i]);
    const float a = -xt * LOG2E;

    // ---- phase 1: moments over all l (one float4 per thread at G=4096) ----
    float acc[RTERMS];
#pragma unroll
    for (int n = 0; n < RTERMS; ++n) acc[n] = 0.0f;

    float gx0[4], eg0[4];   // cached for phase 2 (first/only vec per thread)

    const float4* gv = (const float4*)grid;
    const float4* dv = (const float4*)(density + (size_t)b * G);
    const float4* wv = (const float4*)gw;

    for (int v = t; v < nvec; v += NT) {
        float4 g4 = gv[v];
        float4 d4 = dv[v];
        float4 q4 = wv[v];
        float gx[4] = {g4.x, g4.y, g4.z, g4.w};
        float dd[4] = {d4.x, d4.y, d4.z, d4.w};
        float qq[4] = {q4.x, q4.y, q4.z, q4.w};
#pragma unroll
        for (int j = 0; j < 4; ++j) {
            float gl  = gx[j];
            float gl2 = gl * gl;
            float eg  = exp2f(a * gl2);
            float w   = dd[j] * qq[j] * eg;
            if (v == t) { gx0[j] = gl; eg0[j] = eg; }   // uniform branch
            float gl4 = gl2 * gl2;
            float p0 = w, p1 = w * gl, p2 = w * gl2, p3 = p2 * gl;
#pragma unroll
            for (int k = 0; k < RTERMS / 4; ++k) {  // 4 indep chains, depth 6
                acc[4 * k + 0] += p0; p0 *= gl4;
                acc[4 * k + 1] += p1; p1 *= gl4;
                acc[4 * k + 2] += p2; p2 *= gl4;
                acc[4 * k + 3] += p3; p3 *= gl4;
            }
        }
    }

    // ---- block reduction: wave butterfly, then LDS across 16 waves ----
#pragma unroll
    for (int n = 0; n < RTERMS; ++n) {
        float s = acc[n];
        s += __shfl_xor(s, 1);
        s += __shfl_xor(s, 2);
        s += __shfl_xor(s, 4);
        s += __shfl_xor(s, 8);
        s += __shfl_xor(s, 16);
        s += __shfl_xor(s, 32);
        acc[n] = s;
    }
    __shared__ float part[NWAVES][RTERMS];
    __shared__ float T[RTERMS];
    const int wave = t >> 6, lane = t & 63;
    if (lane == 0) {
#pragma unroll
        for (int n = 0; n < RTERMS; ++n) part[wave][n] = acc[n];
    }
    __syncthreads();
    if (t < RTERMS) {
        const float invfact[RTERMS] = {
            1.0f, 1.0f, 0.5f, 1.6666667e-1f, 4.1666667e-2f, 8.3333333e-3f,
            1.3888889e-3f, 1.9841270e-4f, 2.4801587e-5f, 2.7557319e-6f,
            2.7557319e-7f, 2.5052108e-8f, 2.0876757e-9f, 1.6059044e-10f,
            1.1470746e-11f, 7.6471637e-13f, 4.7794773e-14f, 2.8114573e-15f,
            1.5619207e-16f, 8.2206352e-18f, 4.1103176e-19f, 1.9572941e-20f,
            8.8967914e-22f, 3.8681702e-23f};
        float s = 0.0f;
#pragma unroll
        for (int w2 = 0; w2 < NWAVES; ++w2) s += part[w2][t];
        // fold 0.5*xt here so phase 2 skips the per-element scale
        float cf = 0.5f * xt * exp2f((float)t * __log2f(2.0f * xt)) * invfact[t];
        T[t] = s * cf;
    }
    __syncthreads();

    // ---- phase 2: evaluate the row; T in registers, even/odd-split Horner ----
    float Tr[RTERMS];
#pragma unroll
    for (int n = 0; n < RTERMS; ++n) Tr[n] = T[n];

    float4* ov = (float4*)(out + ((size_t)b * C + i) * G);
    for (int v = t; v < nvec; v += NT) {
        float gxl[4], egl[4];
        if (v == t) {       // fast path: cached from phase 1 (l == m)
#pragma unroll
            for (int j = 0; j < 4; ++j) { gxl[j] = gx0[j]; egl[j] = eg0[j]; }
        } else {            // generality for G > 4*NT (not hit at G=4096)
            float4 g4 = gv[v];
            gxl[0] = g4.x; gxl[1] = g4.y; gxl[2] = g4.z; gxl[3] = g4.w;
#pragma unroll
            for (int j = 0; j < 4; ++j) egl[j] = exp2f(a * gxl[j] * gxl[j]);
        }
        float r[4];
#pragma unroll
        for (int j = 0; j < 4; ++j) {
            float gm = gxl[j], g2 = gm * gm;
            float he = Tr[RTERMS - 2], ho = Tr[RTERMS - 1];
#pragma unroll
            for (int k = RTERMS - 4; k >= 0; k -= 2) {
                he = he * g2 + Tr[k];
                ho = ho * g2 + Tr[k + 1];
            }
            r[j] = egl[j] * (he + gm * ho);
        }
        float4 res; res.x = r[0]; res.y = r[1]; res.z = r[2]; res.w = r[3];
        ov[v] = res;
    }
}

extern "C" void kernel_launch(void* const* d_in, const int* in_sizes, int n_in,
                              void* d_out, int out_size, void* d_ws, size_t ws_size,
                              hipStream_t stream) {
    const float* density = (const float*)d_in[0];   // (B,1,G) fp32
    const float* xi      = (const float*)d_in[1];   // (CH,)
    const float* grid    = (const float*)d_in[2];   // (G,)
    const float* gw      = (const float*)d_in[3];   // (G,)
    float* out = (float*)d_out;

    int CH = in_sizes[1];          // 15
    int G  = in_sizes[2];          // 4096
    int B  = in_sizes[0] / G;      // 16

    gcl_fused<<<dim3(CH + 1, B), NT, 0, stream>>>(density, xi, grid, gw, out, G, CH);
}

// Round 2
// 68.211 us; speedup vs baseline: 1.0087x; 1.0087x over previous
//
#include <hip/hip_runtime.h>
#include <math.h>

// GlobalConvolutionalLayer, fully fused single kernel.
// out[b,i,m] = 0.5*xt_i * sum_l den[b,l]*gw[l]*exp(-xt_i*(g_l-g_m)^2), i < CH(=15)
// out[b,CH,m] = den[b,m].            xt_i = 1 + exp(-xi_i) in (1.37, 3.72).
//
// Mercer/Taylor separation (grid in [0,1], 2*xt*gl*gm <= 7.44):
//   exp(-xt (x-y)^2) = e^{-xt x^2} e^{-xt y^2} sum_n (2 xt)^n (x y)^n / n!
// RTERMS=24 -> absolute tail error ~1e-2; all terms >= 0 (stable).
//
// One block per (i,b), 1024 threads (16 waves/CU = 4 waves/SIMD).
// G==4096 specialization: each thread owns exactly ONE float4 -> zero loops,
// zero runtime branches in the hot path; g and e^{-xt g^2} live in registers
// across both phases (l == m index identity).
//
// NOTE (session journal): bench dur_us ~68.8 includes a fixed ~41.5us 256MiB
// workspace-poison fill (top-5 rocprof dispatches are all fillBufferAligned)
// plus ~24us of tiny reset dispatches; the kernel itself is ~2.6us (never
// appears in top-5 => <40.6us; issue-bound model says ~2.2us). This round
// discriminates: if dur stays ~68, the harness floor (~66us) is confirmed.

#define RTERMS 24
#define NT 1024
#define NWAVES (NT / 64)
#define LOG2E 1.4426950408889634f

__device__ __forceinline__ float reduce_and_eval_setup(
        float acc[RTERMS], float xt, int t, float (*part)[RTERMS], float* T) {
    // ---- wave butterfly over 64 lanes ----
#pragma unroll
    for (int n = 0; n < RTERMS; ++n) {
        float s = acc[n];
        s += __shfl_xor(s, 1);
        s += __shfl_xor(s, 2);
        s += __shfl_xor(s, 4);
        s += __shfl_xor(s, 8);
        s += __shfl_xor(s, 16);
        s += __shfl_xor(s, 32);
        acc[n] = s;
    }
    const int wave = t >> 6, lane = t & 63;
    if (lane == 0) {
#pragma unroll
        for (int n = 0; n < RTERMS; ++n) part[wave][n] = acc[n];
    }
    __syncthreads();
    if (t < RTERMS) {
        const float invfact[RTERMS] = {
            1.0f, 1.0f, 0.5f, 1.6666667e-1f, 4.1666667e-2f, 8.3333333e-3f,
            1.3888889e-3f, 1.9841270e-4f, 2.4801587e-5f, 2.7557319e-6f,
            2.7557319e-7f, 2.5052108e-8f, 2.0876757e-9f, 1.6059044e-10f,
            1.1470746e-11f, 7.6471637e-13f, 4.7794773e-14f, 2.8114573e-15f,
            1.5619207e-16f, 8.2206352e-18f, 4.1103176e-19f, 1.9572941e-20f,
            8.8967914e-22f, 3.8681702e-23f};
        float s = 0.0f;
#pragma unroll
        for (int w2 = 0; w2 < NWAVES; ++w2) s += part[w2][t];
        // fold 0.5*xt here so phase 2 skips the per-element scale
        float cf = 0.5f * xt * exp2f((float)t * __log2f(2.0f * xt)) * invfact[t];
        T[t] = s * cf;
    }
    __syncthreads();
    return 0.0f;
}

// ---------------- G == 4096 specialization: 1 float4 / thread ----------------
__global__ __launch_bounds__(NT, 4) void gcl_fused_g4096(
        const float* __restrict__ density, const float* __restrict__ xi,
        const float* __restrict__ grid, const float* __restrict__ gw,
        float* __restrict__ out, int CH) {
    const int i = blockIdx.x;
    const int b = blockIdx.y;
    const int C = CH + 1;
    const int t = threadIdx.x;
    const int G = 4 * NT;

    if (i == CH) {  // raw density channel: one float4 per thread
        ((float4*)(out + ((size_t)b * C + CH) * G))[t] =
            ((const float4*)(density + (size_t)b * G))[t];
        return;
    }

    const float xt = 1.0f + __expf(-xi[i]);
    const float a = -xt * LOG2E;

    // ---- phase 1: moments S[n] = sum_l W e^{-xt gl^2} gl^n ----
    const float4 g4 = ((const float4*)grid)[t];
    const float4 d4 = ((const float4*)(density + (size_t)b * G))[t];
    const float4 q4 = ((const float4*)gw)[t];
    float gx[4] = {g4.x, g4.y, g4.z, g4.w};
    float dd[4] = {d4.x, d4.y, d4.z, d4.w};
    float qq[4] = {q4.x, q4.y, q4.z, q4.w};
    float eg[4];

    float acc[RTERMS];
#pragma unroll
    for (int n = 0; n < RTERMS; ++n) acc[n] = 0.0f;

#pragma unroll
    for (int j = 0; j < 4; ++j) {
        float gl  = gx[j];
        float gl2 = gl * gl;
        float e   = exp2f(a * gl2);
        eg[j] = e;                       // register-cached for phase 2
        float w   = dd[j] * qq[j] * e;
        float gl4 = gl2 * gl2;
        float p0 = w, p1 = w * gl, p2 = w * gl2, p3 = p2 * gl;
#pragma unroll
        for (int k = 0; k < RTERMS / 4; ++k) {  // 4 indep chains, depth 6
            acc[4 * k + 0] += p0; p0 *= gl4;
            acc[4 * k + 1] += p1; p1 *= gl4;
            acc[4 * k + 2] += p2; p2 *= gl4;
            acc[4 * k + 3] += p3; p3 *= gl4;
        }
    }

    // ---- reduce across 16 waves; T[n] = 0.5*xt*(2xt)^n/n! * S[n] ----
    __shared__ float part[NWAVES][RTERMS];
    __shared__ float T[RTERMS];
    reduce_and_eval_setup(acc, xt, t, part, T);

    // ---- phase 2: even/odd-split Horner on cached g, e^{-xt g^2} ----
    float Tr[RTERMS];
#pragma unroll
    for (int n = 0; n < RTERMS; ++n) Tr[n] = T[n];

    float r[4];
#pragma unroll
    for (int j = 0; j < 4; ++j) {
        float gm = gx[j], g2 = gm * gm;
        float he = Tr[RTERMS - 2], ho = Tr[RTERMS - 1];
#pragma unroll
        for (int k = RTERMS - 4; k >= 0; k -= 2) {
            he = he * g2 + Tr[k];
            ho = ho * g2 + Tr[k + 1];
        }
        r[j] = eg[j] * (he + gm * ho);
    }
    float4 res; res.x = r[0]; res.y = r[1]; res.z = r[2]; res.w = r[3];
    ((float4*)(out + ((size_t)b * C + i) * G))[t] = res;
}

// ---------------- generic fallback (any G multiple of 4) ----------------
__global__ __launch_bounds__(NT, 4) void gcl_fused_gen(
        const float* __restrict__ density, const float* __restrict__ xi,
        const float* __restrict__ grid, const float* __restrict__ gw,
        float* __restrict__ out, int G, int CH) {
    const int i = blockIdx.x;
    const int b = blockIdx.y;
    const int C = CH + 1;
    const int t = threadIdx.x;
    const int nvec = G >> 2;

    if (i == CH) {
        const float4* src = (const float4*)(density + (size_t)b * G);
        float4* dst = (float4*)(out + ((size_t)b * C + CH) * G);
        for (int v = t; v < nvec; v += NT) dst[v] = src[v];
        return;
    }

    const float xt = 1.0f + __expf(-xi[i]);
    const float a = -xt * LOG2E;

    float acc[RTERMS];
#pragma unroll
    for (int n = 0; n < RTERMS; ++n) acc[n] = 0.0f;

    const float4* gv = (const float4*)grid;
    const float4* dv = (const float4*)(density + (size_t)b * G);
    const float4* wv = (const float4*)gw;

    for (int v = t; v < nvec; v += NT) {
        float4 g4 = gv[v];
        float4 d4 = dv[v];
        float4 q4 = wv[v];
        float gx[4] = {g4.x, g4.y, g4.z, g4.w};
        float dd[4] = {d4.x, d4.y, d4.z, d4.w};
        float qq[4] = {q4.x, q4.y, q4.z, q4.w};
#pragma unroll
        for (int j = 0; j < 4; ++j) {
            float gl  = gx[j];
            float gl2 = gl * gl;
            float w   = dd[j] * qq[j] * exp2f(a * gl2);
            float gl4 = gl2 * gl2;
            float p0 = w, p1 = w * gl, p2 = w * gl2, p3 = p2 * gl;
#pragma unroll
            for (int k = 0; k < RTERMS / 4; ++k) {
                acc[4 * k + 0] += p0; p0 *= gl4;
                acc[4 * k + 1] += p1; p1 *= gl4;
                acc[4 * k + 2] += p2; p2 *= gl4;
                acc[4 * k + 3] += p3; p3 *= gl4;
            }
        }
    }

    __shared__ float part[NWAVES][RTERMS];
    __shared__ float T[RTERMS];
    reduce_and_eval_setup(acc, xt, t, part, T);

    float Tr[RTERMS];
#pragma unroll
    for (int n = 0; n < RTERMS; ++n) Tr[n] = T[n];

    float4* ov = (float4*)(out + ((size_t)b * C + i) * G);
    for (int v = t; v < nvec; v += NT) {
        float4 g4 = gv[v];
        float gxl[4] = {g4.x, g4.y, g4.z, g4.w};
        float r[4];
#pragma unroll
        for (int j = 0; j < 4; ++j) {
            float gm = gxl[j], g2 = gm * gm;
            float he = Tr[RTERMS - 2], ho = Tr[RTERMS - 1];
#pragma unroll
            for (int k = RTERMS - 4; k >= 0; k -= 2) {
                he = he * g2 + Tr[k];
                ho = ho * g2 + Tr[k + 1];
            }
            r[j] = exp2f(a * g2) * (he + gm * ho);
        }
        float4 res; res.x = r[0]; res.y = r[1]; res.z = r[2]; res.w = r[3];
        ov[v] = res;
    }
}

extern "C" void kernel_launch(void* const* d_in, const int* in_sizes, int n_in,
                              void* d_out, int out_size, void* d_ws, size_t ws_size,
                              hipStream_t stream) {
    const float* density = (const float*)d_in[0];   // (B,1,G) fp32
    const float* xi      = (const float*)d_in[1];   // (CH,)
    const float* grid    = (const float*)d_in[2];   // (G,)
    const float* gw      = (const float*)d_in[3];   // (G,)
    float* out = (float*)d_out;

    int CH = in_sizes[1];          // 15
    int G  = in_sizes[2];          // 4096
    int B  = in_sizes[0] / G;      // 16

    if (G == 4 * NT) {
        gcl_fused_g4096<<<dim3(CH + 1, B), NT, 0, stream>>>(
            density, xi, grid, gw, out, CH);
    } else {
        gcl_fused_gen<<<dim3(CH + 1, B), NT, 0, stream>>>(
            density, xi, grid, gw, out, G, CH);
    }
}